// Round 5
// baseline (1215.309 us; speedup 1.0000x reference)
//
#include <hip/hip_runtime.h>

typedef __attribute__((ext_vector_type(8))) short short8;
typedef __attribute__((ext_vector_type(4))) float floatx4;
#define MFMA __builtin_amdgcn_mfma_f32_16x16x32_bf16

__device__ inline short to_bf16s(float f) {
    unsigned u = __builtin_bit_cast(unsigned, f);
    unsigned r = u + 0x7FFFu + ((u >> 16) & 1u);
    return (short)(r >> 16);
}

__device__ inline short8 ld8f(const float* p) {
    float4 f0 = *(const float4*)p, f1 = *(const float4*)(p + 4);
    short8 r;
    r[0] = to_bf16s(f0.x); r[1] = to_bf16s(f0.y);
    r[2] = to_bf16s(f0.z); r[3] = to_bf16s(f0.w);
    r[4] = to_bf16s(f1.x); r[5] = to_bf16s(f1.y);
    r[6] = to_bf16s(f1.z); r[7] = to_bf16s(f1.w);
    return r;
}

__device__ inline void dma16(const short* g, short* l) {
    __builtin_amdgcn_global_load_lds(
        (const __attribute__((address_space(1))) unsigned int*)(const void*)g,
        (__attribute__((address_space(3))) unsigned int*)(void*)l, 16, 0, 0);
}

// device-scope grid barrier: monotonic counter, per-phase target.
__device__ inline void gbar(unsigned* cnt, unsigned target) {
    __threadfence();
    __syncthreads();
    if (threadIdx.x == 0) {
        __hip_atomic_fetch_add(cnt, 1u, __ATOMIC_ACQ_REL, __HIP_MEMORY_SCOPE_AGENT);
        while (__hip_atomic_load(cnt, __ATOMIC_ACQUIRE, __HIP_MEMORY_SCOPE_AGENT) < target)
            __builtin_amdgcn_s_sleep(2);
    }
    __syncthreads();
    __threadfence();
}

struct Args {
    const float *x, *adj, *W2, *b2v;
    const float *Wr0, *Wo0, *lb1, *Wr1, *Wo1, *lb2, *Wr2, *Wo2, *lb3;
    const float *W1, *bm1;
    unsigned* cnt;
    short *W2T, *W1T, *BB0, *BB1, *BB2, *adjS;
    short *HP0, *HP1, *HP2, *HP3, *HT0, *HT1, *HT2;
    short *AG0, *AG1, *AG2;
    float* out;
};

// grid 512 x 256. 2 blocks/CU co-resident (LDS 48KB, VGPR<=256).
__global__ __launch_bounds__(256, 2) void mono(Args a) {
    __shared__ __align__(16) short smem[24576];  // 48 KB
    int tid = threadIdx.x, bid = blockIdx.x;
    int lane = tid & 63, w = tid >> 6, wr = w >> 1, wc = w & 1;
    int quad = lane >> 4, l15 = lane & 15;
    unsigned tgt = 512;

    // ================= P0: weight transposes (480 jobs) =================
    {
        short* tile = smem;  // 32x33
        int tx = tid & 31, ty = tid >> 5;
        if (bid < 192) {  // W2 [1536][128] -> W2T [128][1536]
            int bx = (bid & 3) * 32, by = (bid >> 2) * 32;
            for (int i = ty; i < 32; i += 8)
                tile[i * 33 + tx] = to_bf16s(a.W2[(size_t)(by + i) * 128 + bx + tx]);
            __syncthreads();
            for (int i = ty; i < 32; i += 8)
                a.W2T[(size_t)(bx + i) * 1536 + by + tx] = tile[tx * 33 + i];
        } else if (bid < 384) {  // W1 [128][1536] -> W1T [1536][128]
            int u = bid - 192;
            int bx = (u % 48) * 32, by = (u / 48) * 32;
            for (int i = ty; i < 32; i += 8)
                tile[i * 33 + tx] = to_bf16s(a.W1[(size_t)(by + i) * 1536 + bx + tx]);
            __syncthreads();
            for (int i = ty; i < 32; i += 8)
                a.W1T[(size_t)(bx + i) * 128 + by + tx] = tile[tx * 33 + i];
        } else if (bid < 480) {  // BB_l [128 j][256 k] = {Wr[k][j] | Wo[k-128][j]}
            int u = bid - 384, l = u / 32, v = u % 32;
            int j0 = (v & 3) * 32, k0 = (v >> 2) * 32;
            const float* Wr = l == 0 ? a.Wr0 : l == 1 ? a.Wr1 : a.Wr2;
            const float* Wo = l == 0 ? a.Wo0 : l == 1 ? a.Wo1 : a.Wo2;
            short* BB = l == 0 ? a.BB0 : l == 1 ? a.BB1 : a.BB2;
            for (int i = ty; i < 32; i += 8) {
                int k = k0 + i;
                const float* sr = (k < 128) ? Wr + (size_t)k * 128 : Wo + (size_t)(k - 128) * 128;
                tile[i * 33 + tx] = to_bf16s(sr[j0 + tx]);
            }
            __syncthreads();
            for (int i = ty; i < 32; i += 8)
                BB[(size_t)(j0 + i) * 256 + k0 + tx] = tile[tx * 33 + i];
        }
    }
    gbar(a.cnt, tgt); tgt += 512;

    // ================= P1: mlp2 (512 jobs) + adjS (4 rows/block) =================
    {
        short* As = smem;          // 32*72
        short* Bs = smem + 2304;   // 64*64
        short* Ct = smem + 6400;   // 32*64
        int mt = bid >> 1, ch = bid & 1;
        int m0 = mt * 32, c0 = ch * 64;
        int srow = tid >> 3, scol = (tid & 7) * 8;
        const float* Ax = a.x + (size_t)(m0 + srow) * 1536 + scol;
        const short* Bw = a.W2T + (size_t)(c0 + (tid >> 3)) * 1536 + (tid & 7) * 8;
        short* Bl = Bs + tid * 8;
        short8 ra = ld8f(Ax);
        floatx4 acc[2];
        #pragma unroll
        for (int j = 0; j < 2; ++j)
            #pragma unroll
            for (int r = 0; r < 4; ++r) acc[j][r] = 0.f;

        for (int it = 0; it < 24; ++it) {
            *(short8*)(As + srow * 72 + scol) = ra;
            dma16(Bw + it * 64, Bl);
            dma16(Bw + it * 64 + (size_t)32 * 1536, Bl + 2048);
            __syncthreads();
            if (it < 23) ra = ld8f(Ax + (it + 1) * 64);
            const short* Ar = As + (wr * 16 + l15) * 72;
            const short* Br = Bs + (wc * 32 + l15) * 64;
            #pragma unroll
            for (int ks = 0; ks < 2; ++ks) {
                int kof = ks * 32 + quad * 8;
                short8 af = *(const short8*)(Ar + kof);
                short8 b0 = *(const short8*)(Br + kof);
                short8 b1 = *(const short8*)(Br + 16 * 64 + kof);
                acc[0] = MFMA(af, b0, acc[0], 0, 0, 0);
                acc[1] = MFMA(af, b1, acc[1], 0, 0, 0);
            }
            __syncthreads();
        }
        #pragma unroll
        for (int tj = 0; tj < 2; ++tj) {
            int col = wc * 32 + tj * 16 + l15;
            float bv = a.b2v[c0 + col];
            int r0 = wr * 16 + quad * 4;
            #pragma unroll
            for (int r = 0; r < 4; ++r)
                Ct[(r0 + r) * 64 + col] = to_bf16s(acc[tj][r] + bv);
        }
        __syncthreads();
        {   // HP0[(n*4+b)][c0+..]
            int lr = tid >> 3, j0 = (tid & 7) * 8;
            int mr = m0 + lr, n = mr & 2047, b = mr >> 11;
            *(short8*)(a.HP0 + (size_t)(n * 4 + b) * 128 + c0 + j0) =
                *(const short8*)(Ct + lr * 64 + j0);
        }
        {   // HT0[b*128+c0+j][n0..]
            int j = tid >> 2, nq = (tid & 3) * 8;
            int b = m0 >> 11, n0 = m0 & 2047;
            short tmp[8];
            #pragma unroll
            for (int e = 0; e < 8; ++e) tmp[e] = Ct[(nq + e) * 64 + j];
            *(short8*)(a.HT0 + (size_t)(b * 128 + c0 + j) * 2048 + n0 + nq) =
                *(const short8*)tmp;
        }
        __syncthreads();
        // adjS rows bid*4 .. +3
        float* red = (float*)smem;
        for (int rr = 0; rr < 4; ++rr) {
            int row = bid * 4 + rr;
            const float* src = a.adj + (size_t)row * 2048 + tid * 8;
            float4 f0 = *(const float4*)src;
            float4 f1 = *(const float4*)(src + 4);
            float s = f0.x + f0.y + f0.z + f0.w + f1.x + f1.y + f1.z + f1.w;
            red[tid] = s;
            __syncthreads();
            for (int st = 128; st > 0; st >>= 1) {
                if (tid < st) red[tid] += red[tid + st];
                __syncthreads();
            }
            float dsum = red[0];
            __syncthreads();
            dsum = dsum < 1.f ? 1.f : dsum;
            float inv = 1.f / dsum;
            short8 o;
            o[0] = to_bf16s(f0.x * inv); o[1] = to_bf16s(f0.y * inv);
            o[2] = to_bf16s(f0.z * inv); o[3] = to_bf16s(f0.w * inv);
            o[4] = to_bf16s(f1.x * inv); o[5] = to_bf16s(f1.y * inv);
            o[6] = to_bf16s(f1.z * inv); o[7] = to_bf16s(f1.w * inv);
            *(short8*)(a.adjS + (size_t)row * 2048 + tid * 8) = o;
        }
    }
    gbar(a.cnt, tgt); tgt += 512;

    // ================= 3 x (agg -> combine) =================
    const short* HTin[3] = {a.HT0, a.HT1, a.HT2};
    short* HPbuf[4] = {a.HP0, a.HP1, a.HP2, a.HP3};
    short* AG[3] = {a.AG0, a.AG1, a.AG2};
    short* HTo[3] = {a.HT1, a.HT2, nullptr};
    const short* BBl[3] = {a.BB0, a.BB1, a.BB2};
    const float* LB[3] = {a.lb1, a.lb2, a.lb3};

    for (int l = 0; l < 3; ++l) {
        {   // ---- agg: AG[l][(n*4+b)*128 + col] = adjS @ HTin^T ----
            short* As = smem;          // 32*64
            short* Bs = smem + 2048;   // 64*64
            int nt = bid >> 3, b = (bid >> 1) & 3, ch = bid & 1;
            int n0 = nt * 32, c0 = ch * 64;
            const short* Aa = a.adjS + (size_t)(n0 + (tid >> 3)) * 2048 + (tid & 7) * 8;
            const short* Bh = HTin[l] + (size_t)(b * 128 + c0 + (tid >> 3)) * 2048 + (tid & 7) * 8;
            short* Al = As + tid * 8;
            short* Bl = Bs + tid * 8;
            floatx4 acc[2];
            #pragma unroll
            for (int j = 0; j < 2; ++j)
                #pragma unroll
                for (int r = 0; r < 4; ++r) acc[j][r] = 0.f;
            for (int it = 0; it < 32; ++it) {
                dma16(Aa + it * 64, Al);
                dma16(Bh + it * 64, Bl);
                dma16(Bh + it * 64 + (size_t)32 * 2048, Bl + 2048);
                __syncthreads();
                const short* Ar = As + (wr * 16 + l15) * 64;
                const short* Br = Bs + (wc * 32 + l15) * 64;
                #pragma unroll
                for (int ks = 0; ks < 2; ++ks) {
                    int kof = ks * 32 + quad * 8;
                    short8 af = *(const short8*)(Ar + kof);
                    short8 b0 = *(const short8*)(Br + kof);
                    short8 b1 = *(const short8*)(Br + 16 * 64 + kof);
                    acc[0] = MFMA(af, b0, acc[0], 0, 0, 0);
                    acc[1] = MFMA(af, b1, acc[1], 0, 0, 0);
                }
                __syncthreads();
            }
            short* AGp = AG[l];
            #pragma unroll
            for (int tj = 0; tj < 2; ++tj) {
                int col = wc * 32 + tj * 16 + l15;
                int r0 = wr * 16 + quad * 4;
                #pragma unroll
                for (int r = 0; r < 4; ++r)
                    AGp[(size_t)((n0 + r0 + r) * 4 + b) * 128 + c0 + col] =
                        to_bf16s(acc[tj][r]);
            }
        }
        gbar(a.cnt, tgt); tgt += 512;

        {   // ---- combine: HP[l+1] = act([AG|HP[l]] @ BB^T + bias) ----
            short* A2s = smem;          // 4 blocks of 32x64
            short* Bs = smem + 8192;    // 4 blocks of 64x64
            int mt = bid >> 1, ch = bid & 1;
            int m0 = mt * 32, c0 = ch * 64;
            #pragma unroll
            for (int r = 0; r < 4; ++r) {
                const short* srcb = (r < 2) ? AG[l] : HPbuf[l];
                const short* src = srcb + (size_t)(m0 + (tid >> 3)) * 128 +
                                   (r & 1) * 64 + (tid & 7) * 8;
                dma16(src, A2s + r * 2048 + tid * 8);
            }
            #pragma unroll
            for (int r = 0; r < 8; ++r) {
                int kb = r >> 1, half = r & 1;
                const short* src = BBl[l] + (size_t)(c0 + half * 32 + (tid >> 3)) * 256 +
                                   kb * 64 + (tid & 7) * 8;
                dma16(src, Bs + kb * 4096 + (half * 256 + tid) * 8);
            }
            __syncthreads();
            floatx4 acc[2];
            #pragma unroll
            for (int j = 0; j < 2; ++j)
                #pragma unroll
                for (int r = 0; r < 4; ++r) acc[j][r] = 0.f;
            #pragma unroll
            for (int kb = 0; kb < 4; ++kb) {
                const short* Ar = A2s + kb * 2048 + (wr * 16 + l15) * 64;
                const short* Br = Bs + kb * 4096 + (wc * 32 + l15) * 64;
                #pragma unroll
                for (int ks = 0; ks < 2; ++ks) {
                    int kof = ks * 32 + quad * 8;
                    short8 af = *(const short8*)(Ar + kof);
                    short8 b0 = *(const short8*)(Br + kof);
                    short8 b1 = *(const short8*)(Br + 16 * 64 + kof);
                    acc[0] = MFMA(af, b0, acc[0], 0, 0, 0);
                    acc[1] = MFMA(af, b1, acc[1], 0, 0, 0);
                }
            }
            __syncthreads();
            short* Ct = A2s;
            int relu = (l < 2);
            #pragma unroll
            for (int tj = 0; tj < 2; ++tj) {
                int col = wc * 32 + tj * 16 + l15;
                float bv = LB[l][c0 + col];
                int r0 = wr * 16 + quad * 4;
                #pragma unroll
                for (int r = 0; r < 4; ++r) {
                    float v = acc[tj][r] + bv;
                    if (relu) v = v > 0.f ? v : 0.f;
                    Ct[(r0 + r) * 64 + col] = to_bf16s(v);
                }
            }
            __syncthreads();
            {
                int lr = tid >> 3, j0 = (tid & 7) * 8;
                *(short8*)(HPbuf[l + 1] + (size_t)(m0 + lr) * 128 + c0 + j0) =
                    *(const short8*)(Ct + lr * 64 + j0);
            }
            if (HTo[l]) {
                int j = tid & 63, b = tid >> 6, n0 = m0 >> 2;
                short tmp[8];
                #pragma unroll
                for (int e = 0; e < 8; ++e) tmp[e] = Ct[(e * 4 + b) * 64 + j];
                *(short8*)(HTo[l] + (size_t)(b * 128 + c0 + j) * 2048 + n0) =
                    *(const short8*)tmp;
            }
        }
        gbar(a.cnt, tgt); tgt += 512;
    }

    // ================= P8: mlp1 (1536 jobs, 3 per block) =================
    for (int rep = 0; rep < 3; ++rep) {
        int jj = rep * 512 + bid;
        int mt = jj / 12, ct = jj - mt * 12;
        int m0 = mt * 64, c0 = ct * 128;
        short* As = smem;          // 2 blocks of 64x64
        short* Bs = smem + 8192;   // 2 blocks of 128x64
        #pragma unroll
        for (int r = 0; r < 4; ++r) {
            int kb = r >> 1, half = r & 1;
            const short* src = a.HP3 + (size_t)(m0 + half * 32 + (tid >> 3)) * 128 +
                               kb * 64 + (tid & 7) * 8;
            dma16(src, As + kb * 4096 + (half * 256 + tid) * 8);
        }
        #pragma unroll
        for (int r = 0; r < 8; ++r) {
            int kb = r >> 2, q = r & 3;
            const short* src = a.W1T + (size_t)(c0 + q * 32 + (tid >> 3)) * 128 +
                               kb * 64 + (tid & 7) * 8;
            dma16(src, Bs + kb * 8192 + (q * 256 + tid) * 8);
        }
        __syncthreads();
        floatx4 acc[2][4];
        #pragma unroll
        for (int i = 0; i < 2; ++i)
            #pragma unroll
            for (int j = 0; j < 4; ++j)
                #pragma unroll
                for (int r = 0; r < 4; ++r) acc[i][j][r] = 0.f;
        #pragma unroll
        for (int kb = 0; kb < 2; ++kb) {
            const short* Arb = As + kb * 4096;
            const short* Brb = Bs + kb * 8192;
            #pragma unroll
            for (int ks = 0; ks < 2; ++ks) {
                int kof = ks * 32 + quad * 8;
                short8 af[2], bf[4];
                #pragma unroll
                for (int i = 0; i < 2; ++i)
                    af[i] = *(const short8*)(Arb + (wr * 32 + i * 16 + l15) * 64 + kof);
                #pragma unroll
                for (int j = 0; j < 4; ++j)
                    bf[j] = *(const short8*)(Brb + (wc * 64 + j * 16 + l15) * 64 + kof);
                #pragma unroll
                for (int i = 0; i < 2; ++i)
                    #pragma unroll
                    for (int j = 0; j < 4; ++j)
                        acc[i][j] = MFMA(af[i], bf[j], acc[i][j], 0, 0, 0);
            }
        }
        #pragma unroll
        for (int i = 0; i < 2; ++i)
            #pragma unroll
            for (int j = 0; j < 4; ++j) {
                int col = c0 + wc * 64 + j * 16 + l15;
                float bv = a.bm1[col];
                int r0 = m0 + wr * 32 + i * 16 + quad * 4;
                #pragma unroll
                for (int r = 0; r < 4; ++r) {
                    int mp = r0 + r;  // n*4+b
                    int orow = (mp & 3) * 2048 + (mp >> 2);
                    a.out[(size_t)orow * 1536 + col] = acc[i][j][r] + bv;
                }
            }
        __syncthreads();
    }
}

extern "C" void kernel_launch(void* const* d_in, const int* in_sizes, int n_in,
                              void* d_out, int out_size, void* d_ws, size_t ws_size,
                              hipStream_t stream) {
    char* ws = (char*)d_ws;
    size_t off = 0;
    auto alloc = [&](size_t bytes) -> char* {
        char* p = ws + off;
        off = (off + bytes + 255) & ~(size_t)255;
        return p;
    };
    unsigned* cnt = (unsigned*)alloc(256);
    Args a;
    a.x   = (const float*)d_in[0];  a.adj = (const float*)d_in[1];
    a.W2  = (const float*)d_in[2];  a.b2v = (const float*)d_in[3];
    a.Wr0 = (const float*)d_in[4];  a.Wo0 = (const float*)d_in[5];
    a.lb1 = (const float*)d_in[6];  a.Wr1 = (const float*)d_in[7];
    a.Wo1 = (const float*)d_in[8];  a.lb2 = (const float*)d_in[9];
    a.Wr2 = (const float*)d_in[10]; a.Wo2 = (const float*)d_in[11];
    a.lb3 = (const float*)d_in[12]; a.W1  = (const float*)d_in[13];
    a.bm1 = (const float*)d_in[14];
    a.cnt  = cnt;
    a.W2T  = (short*)alloc(128 * 1536 * 2);
    a.W1T  = (short*)alloc(1536 * 128 * 2);
    a.BB0  = (short*)alloc(128 * 256 * 2);
    a.BB1  = (short*)alloc(128 * 256 * 2);
    a.BB2  = (short*)alloc(128 * 256 * 2);
    a.adjS = (short*)alloc((size_t)2048 * 2048 * 2);
    a.HP0  = (short*)alloc((size_t)8192 * 128 * 2);
    a.HP1  = (short*)alloc((size_t)8192 * 128 * 2);
    a.HP2  = (short*)alloc((size_t)8192 * 128 * 2);
    a.HP3  = (short*)alloc((size_t)8192 * 128 * 2);
    a.HT0  = (short*)alloc((size_t)512 * 2048 * 2);
    a.HT1  = (short*)alloc((size_t)512 * 2048 * 2);
    a.HT2  = (short*)alloc((size_t)512 * 2048 * 2);
    a.AG0  = (short*)alloc((size_t)8192 * 128 * 2);
    a.AG1  = (short*)alloc((size_t)8192 * 128 * 2);
    a.AG2  = (short*)alloc((size_t)8192 * 128 * 2);
    a.out  = (float*)d_out;

    hipMemsetAsync(cnt, 0, 256, stream);
    mono<<<512, 256, 0, stream>>>(a);
}

// Round 6
// 307.456 us; speedup vs baseline: 3.9528x; 3.9528x over previous
//
#include <hip/hip_runtime.h>

typedef __attribute__((ext_vector_type(8))) short short8;
typedef __attribute__((ext_vector_type(4))) float floatx4;
#define MFMA __builtin_amdgcn_mfma_f32_16x16x32_bf16

__device__ inline short to_bf16s(float f) {
    unsigned u = __builtin_bit_cast(unsigned, f);
    unsigned r = u + 0x7FFFu + ((u >> 16) & 1u);
    return (short)(r >> 16);
}

__device__ inline short8 ld8f(const float* p) {
    float4 f0 = *(const float4*)p, f1 = *(const float4*)(p + 4);
    short8 r;
    r[0] = to_bf16s(f0.x); r[1] = to_bf16s(f0.y);
    r[2] = to_bf16s(f0.z); r[3] = to_bf16s(f0.w);
    r[4] = to_bf16s(f1.x); r[5] = to_bf16s(f1.y);
    r[6] = to_bf16s(f1.z); r[7] = to_bf16s(f1.w);
    return r;
}

__device__ inline void dma16(const short* g, short* l) {
    __builtin_amdgcn_global_load_lds(
        (const __attribute__((address_space(1))) unsigned int*)(const void*)g,
        (__attribute__((address_space(3))) unsigned int*)(void*)l, 16, 0, 0);
}

// hierarchical grid barrier: 8 relaxed sub-counters -> master -> release flag;
// pollers do RELAXED loads on the (read-only) flag line with long s_sleep.
__device__ inline void gbar(unsigned* bar, unsigned phase, int bid) {
    __syncthreads();
    if (threadIdx.x == 0) {
        __threadfence();  // release prior writes to device scope
        unsigned old = __hip_atomic_fetch_add(&bar[(bid & 7) * 16], 1u,
                                              __ATOMIC_RELAXED, __HIP_MEMORY_SCOPE_AGENT);
        if ((old & 31u) == 31u) {  // last of the 32 blocks in this sub-group
            unsigned m = __hip_atomic_fetch_add(&bar[128], 1u,
                                                __ATOMIC_RELAXED, __HIP_MEMORY_SCOPE_AGENT);
            if ((m & 7u) == 7u)
                __hip_atomic_store(&bar[144], phase, __ATOMIC_RELEASE,
                                   __HIP_MEMORY_SCOPE_AGENT);
        }
        while (__hip_atomic_load(&bar[144], __ATOMIC_RELAXED,
                                 __HIP_MEMORY_SCOPE_AGENT) < phase)
            __builtin_amdgcn_s_sleep(64);
        __threadfence();  // acquire
    }
    __syncthreads();
}

struct Args {
    const float *x, *adj, *W2, *b2v;
    const float *Wr0, *Wo0, *lb1, *Wr1, *Wo1, *lb2, *Wr2, *Wo2, *lb3;
    const float *W1, *bm1;
    unsigned* bar;
    short *adjS, *W1T, *BB0, *BB1, *BB2;
    short *HP0, *HP1, *HP2, *HP3, *HT0, *HT1, *HT2;
    float* out;
};

// grid 256 = 1 block/CU. 4 grid barriers.
__global__ __launch_bounds__(256) void mono2(Args a) {
    __shared__ __align__(16) short smem[24576];  // 48 KB
    int tid = threadIdx.x, bid = blockIdx.x;
    int lane = tid & 63, w = tid >> 6, wr = w >> 1, wc = w & 1;
    int quad = lane >> 4, l15 = lane & 15;
    // staging swizzles (global chunk index per lane; LDS dest stays tid*8)
    int swz8  = (((tid & 7) ^ ((tid >> 3) & 7)) << 3);                       // 8-chunk rows
    int swz16 = ((((tid & 15) & 8) | (((tid & 15) ^ ((tid >> 4) & 7)) & 7)) << 3); // 16-chunk rows

    // ================= P1: mlp2 + adjS + W1T + BB =================
    {
        // ---- mlp2: 64x64 tile job (mt, dt), K=1536, in-kernel W2 staging ----
        int mt = bid >> 1, dt = bid & 1;
        int b = mt >> 5, n0 = (mt & 31) * 64;
        int srow = tid >> 3, scol = (tid & 7) * 8;
        const float* Abase = a.x + (size_t)(mt * 64) * 1536;
        int kk = tid >> 2, j0 = (tid & 3) * 16;
        const float* Bbase = a.W2 + (size_t)kk * 128 + dt * 64 + j0;

        short8 ra0 = ld8f(Abase + (size_t)srow * 1536 + scol);
        short8 ra1 = ld8f(Abase + (size_t)(srow + 32) * 1536 + scol);
        float4 bw0 = *(const float4*)(Bbase);
        float4 bw1 = *(const float4*)(Bbase + 4);
        float4 bw2 = *(const float4*)(Bbase + 8);
        float4 bw3 = *(const float4*)(Bbase + 12);

        floatx4 acc[2][2];
        #pragma unroll
        for (int i = 0; i < 2; ++i)
            #pragma unroll
            for (int j = 0; j < 2; ++j)
                #pragma unroll
                for (int r = 0; r < 4; ++r) acc[i][j][r] = 0.f;

        for (int it = 0; it < 24; ++it) {
            short* As = smem + (it & 1) * 9216;
            short* Bs = As + 4608;
            *(short8*)(As + srow * 72 + scol) = ra0;
            *(short8*)(As + (srow + 32) * 72 + scol) = ra1;
            {
                const float* fw = (const float*)&bw0;
                #pragma unroll
                for (int e = 0; e < 4; ++e) Bs[(j0 + e) * 72 + kk] = to_bf16s(fw[e]);
                fw = (const float*)&bw1;
                #pragma unroll
                for (int e = 0; e < 4; ++e) Bs[(j0 + 4 + e) * 72 + kk] = to_bf16s(fw[e]);
                fw = (const float*)&bw2;
                #pragma unroll
                for (int e = 0; e < 4; ++e) Bs[(j0 + 8 + e) * 72 + kk] = to_bf16s(fw[e]);
                fw = (const float*)&bw3;
                #pragma unroll
                for (int e = 0; e < 4; ++e) Bs[(j0 + 12 + e) * 72 + kk] = to_bf16s(fw[e]);
            }
            __syncthreads();
            if (it + 1 < 24) {
                int ko = (it + 1) * 64;
                ra0 = ld8f(Abase + (size_t)srow * 1536 + ko + scol);
                ra1 = ld8f(Abase + (size_t)(srow + 32) * 1536 + ko + scol);
                const float* Bp = Bbase + (size_t)ko * 128;
                bw0 = *(const float4*)(Bp);
                bw1 = *(const float4*)(Bp + 4);
                bw2 = *(const float4*)(Bp + 8);
                bw3 = *(const float4*)(Bp + 12);
            }
            const short* Arow = As + (wr * 32 + l15) * 72;
            const short* Brow = Bs + (wc * 32 + l15) * 72;
            #pragma unroll
            for (int ks = 0; ks < 2; ++ks) {
                int kof = ks * 32 + quad * 8;
                short8 a0 = *(const short8*)(Arow + kof);
                short8 a1 = *(const short8*)(Arow + 16 * 72 + kof);
                short8 b0 = *(const short8*)(Brow + kof);
                short8 b1 = *(const short8*)(Brow + 16 * 72 + kof);
                acc[0][0] = MFMA(a0, b0, acc[0][0], 0, 0, 0);
                acc[0][1] = MFMA(a0, b1, acc[0][1], 0, 0, 0);
                acc[1][0] = MFMA(a1, b0, acc[1][0], 0, 0, 0);
                acc[1][1] = MFMA(a1, b1, acc[1][1], 0, 0, 0);
            }
            __syncthreads();
        }
        #pragma unroll
        for (int ti = 0; ti < 2; ++ti)
            #pragma unroll
            for (int tj = 0; tj < 2; ++tj) {
                int col = wc * 32 + tj * 16 + l15;
                float bv = a.b2v[dt * 64 + col];
                int row0 = wr * 32 + ti * 16 + quad * 4;
                #pragma unroll
                for (int r = 0; r < 4; ++r)
                    smem[(row0 + r) * 72 + col] = to_bf16s(acc[ti][tj][r] + bv);
            }
        __syncthreads();
        {   // HP0 rows (node*4+b)
            int nl = tid >> 2, c0 = (tid & 3) * 16;
            short8 v0 = *(const short8*)(smem + nl * 72 + c0);
            short8 v1 = *(const short8*)(smem + nl * 72 + c0 + 8);
            short* dst = a.HP0 + (size_t)((n0 + nl) * 4 + b) * 128 + dt * 64 + c0;
            *(short8*)(dst) = v0;
            *(short8*)(dst + 8) = v1;
        }
        {   // HT0 rows (b*128+d)
            int d = tid >> 2, nh = (tid & 3) * 16;
            short tmp[16];
            #pragma unroll
            for (int i = 0; i < 16; ++i) tmp[i] = smem[(nh + i) * 72 + d];
            short* dst = a.HT0 + (size_t)(b * 128 + dt * 64 + d) * 2048 + n0 + nh;
            *(short8*)(dst) = *(const short8*)(tmp);
            *(short8*)(dst + 8) = *(const short8*)(tmp + 8);
        }
        __syncthreads();
        // ---- adjS: rows bid*8 .. +7 ----
        float* red = (float*)smem;
        for (int rr = 0; rr < 8; ++rr) {
            int row = bid * 8 + rr;
            const float* src = a.adj + (size_t)row * 2048 + tid * 8;
            float4 f0 = *(const float4*)src;
            float4 f1 = *(const float4*)(src + 4);
            float s = f0.x + f0.y + f0.z + f0.w + f1.x + f1.y + f1.z + f1.w;
            red[tid] = s;
            __syncthreads();
            for (int st = 128; st > 0; st >>= 1) {
                if (tid < st) red[tid] += red[tid + st];
                __syncthreads();
            }
            float dsum = red[0];
            __syncthreads();
            dsum = dsum < 1.f ? 1.f : dsum;
            float inv = 1.f / dsum;
            short8 o;
            o[0] = to_bf16s(f0.x * inv); o[1] = to_bf16s(f0.y * inv);
            o[2] = to_bf16s(f0.z * inv); o[3] = to_bf16s(f0.w * inv);
            o[4] = to_bf16s(f1.x * inv); o[5] = to_bf16s(f1.y * inv);
            o[6] = to_bf16s(f1.z * inv); o[7] = to_bf16s(f1.w * inv);
            *(short8*)(a.adjS + (size_t)row * 2048 + tid * 8) = o;
        }
        __syncthreads();
        // ---- W1T: blocks 0..191, one 32x32 tile ----
        if (bid < 192) {
            int bx = (bid % 48) * 32, by = (bid / 48) * 32;  // bx = W1 col, by = W1 row(k)
            short* tile = smem;
            int tx = tid & 31, ty = tid >> 5;
            for (int i = ty; i < 32; i += 8)
                tile[i * 33 + tx] = to_bf16s(a.W1[(size_t)(by + i) * 1536 + bx + tx]);
            __syncthreads();
            for (int i = ty; i < 32; i += 8)
                a.W1T[(size_t)(bx + i) * 128 + by + tx] = tile[tx * 33 + i];
            __syncthreads();
        }
        // ---- BB: blocks 160..255 ----
        if (bid >= 160) {
            int u = bid - 160, l = u / 32, v = u % 32;
            int j0b = (v & 3) * 32, k0 = (v >> 2) * 32;
            const float* Wr = l == 0 ? a.Wr0 : l == 1 ? a.Wr1 : a.Wr2;
            const float* Wo = l == 0 ? a.Wo0 : l == 1 ? a.Wo1 : a.Wo2;
            short* BB = l == 0 ? a.BB0 : l == 1 ? a.BB1 : a.BB2;
            short* tile = smem;
            int tx = tid & 31, ty = tid >> 5;
            for (int i = ty; i < 32; i += 8) {
                int k = k0 + i;
                const float* sr = (k < 128) ? Wr + (size_t)k * 128 : Wo + (size_t)(k - 128) * 128;
                tile[i * 33 + tx] = to_bf16s(sr[j0b + tx]);
            }
            __syncthreads();
            for (int i = ty; i < 32; i += 8)
                BB[(size_t)(j0b + i) * 256 + k0 + tx] = tile[tx * 33 + i];
        }
    }
    gbar(a.bar, 1, bid);

    // ================= Layers: fused agg(K=2048) + combine(K=256) =================
    for (int l = 0; l < 3; ++l) {
        const short* HTl = (l == 0) ? a.HT0 : (l == 1) ? a.HT1 : a.HT2;
        const short* HPl = (l == 0) ? a.HP0 : (l == 1) ? a.HP1 : a.HP2;
        short* HPo = (l == 0) ? a.HP1 : (l == 1) ? a.HP2 : a.HP3;
        short* HTo = (l == 0) ? a.HT1 : (l == 1) ? a.HT2 : (short*)0;
        const short* BBl = (l == 0) ? a.BB0 : (l == 1) ? a.BB1 : a.BB2;
        const float* lb = (l == 0) ? a.lb1 : (l == 1) ? a.lb2 : a.lb3;
        int nt = bid >> 2, b = bid & 3;

        short* As0 = smem;           // dbuf 2 x 2048  (32x64)
        short* Bs0 = smem + 4096;    // dbuf 2 x 8192  (128x64)
        const short* Ag = a.adjS + (size_t)(nt * 32 + (tid >> 3)) * 2048 + swz8;
        const short* Bg = HTl + (size_t)(b * 128 + (tid >> 3)) * 2048 + swz8;

        floatx4 acc[4];
        #pragma unroll
        for (int j = 0; j < 4; ++j)
            #pragma unroll
            for (int r = 0; r < 4; ++r) acc[j][r] = 0.f;

        // preload iter 0
        dma16(Ag, As0 + tid * 8);
        #pragma unroll
        for (int r = 0; r < 4; ++r)
            dma16(Bg + (size_t)(r * 32) * 2048, Bs0 + r * 2048 + tid * 8);
        __syncthreads();

        for (int it = 0; it < 32; ++it) {
            int cur = it & 1, nxt = cur ^ 1;
            if (it + 1 < 32) {
                dma16(Ag + (it + 1) * 64, As0 + nxt * 2048 + tid * 8);
                #pragma unroll
                for (int r = 0; r < 4; ++r)
                    dma16(Bg + (it + 1) * 64 + (size_t)(r * 32) * 2048,
                          Bs0 + nxt * 8192 + r * 2048 + tid * 8);
            }
            const short* Ac = As0 + cur * 2048;
            const short* Bc = Bs0 + cur * 8192;
            int Ra = wr * 16 + l15;
            #pragma unroll
            for (int ks = 0; ks < 2; ++ks) {
                int sw = (((ks * 4 + quad) ^ (l15 & 7)) << 3);
                short8 af = *(const short8*)(Ac + Ra * 64 + sw);
                #pragma unroll
                for (int j = 0; j < 4; ++j) {
                    int Rb = wc * 64 + j * 16 + l15;
                    short8 bf = *(const short8*)(Bc + Rb * 64 + sw);
                    acc[j] = MFMA(af, bf, acc[j], 0, 0, 0);
                }
            }
            __syncthreads();
        }

        // ---- stage2 inputs: A2 = [AGG | HP] (32 x 264, unswizzled) ----
        short* A2 = smem;            // 32*264 = 8448
        short* B2 = smem + 8448;     // 128*64 = 8192
        short* OUTb = smem + 16640;  // 32*136 = 4352
        {
            int row0 = wr * 16 + quad * 4;
            #pragma unroll
            for (int j = 0; j < 4; ++j) {
                int jc = wc * 64 + j * 16 + l15;
                #pragma unroll
                for (int r = 0; r < 4; ++r)
                    A2[(row0 + r) * 264 + jc] = to_bf16s(acc[j][r]);
            }
            int rr = tid >> 3, cc = (tid & 7) * 16;
            const short* hsrc = HPl + (size_t)((nt * 32 + rr) * 4 + b) * 128 + cc;
            *(short8*)(A2 + rr * 264 + 128 + cc) = *(const short8*)hsrc;
            *(short8*)(A2 + rr * 264 + 128 + cc + 8) = *(const short8*)(hsrc + 8);
        }
        __syncthreads();

        floatx4 acc2[4];
        #pragma unroll
        for (int j = 0; j < 4; ++j)
            #pragma unroll
            for (int r = 0; r < 4; ++r) acc2[j][r] = 0.f;

        for (int kb = 0; kb < 4; ++kb) {
            #pragma unroll
            for (int r = 0; r < 4; ++r)
                dma16(BBl + (size_t)((tid >> 3) + r * 32) * 256 + kb * 64 + swz8,
                      B2 + r * 2048 + tid * 8);
            __syncthreads();
            int Ra = wr * 16 + l15;
            #pragma unroll
            for (int ks = 0; ks < 2; ++ks) {
                int sw = (((ks * 4 + quad) ^ (l15 & 7)) << 3);
                short8 af = *(const short8*)(A2 + Ra * 264 + kb * 64 + ks * 32 + quad * 8);
                #pragma unroll
                for (int j = 0; j < 4; ++j) {
                    int Rb = wc * 64 + j * 16 + l15;
                    short8 bf = *(const short8*)(B2 + Rb * 64 + sw);
                    acc2[j] = MFMA(af, bf, acc2[j], 0, 0, 0);
                }
            }
            __syncthreads();
        }

        // ---- epilogue ----
        {
            int row0 = wr * 16 + quad * 4;
            #pragma unroll
            for (int j = 0; j < 4; ++j) {
                int jc = wc * 64 + j * 16 + l15;
                float bv = lb[jc];
                #pragma unroll
                for (int r = 0; r < 4; ++r) {
                    float v = acc2[j][r] + bv;
                    if (l < 2) v = v > 0.f ? v : 0.f;
                    OUTb[(row0 + r) * 136 + jc] = to_bf16s(v);
                }
            }
        }
        __syncthreads();
        {
            int rr = tid >> 3, cc = (tid & 7) * 16;
            short* hdst = HPo + (size_t)((nt * 32 + rr) * 4 + b) * 128 + cc;
            *(short8*)hdst = *(const short8*)(OUTb + rr * 136 + cc);
            *(short8*)(hdst + 8) = *(const short8*)(OUTb + rr * 136 + cc + 8);
        }
        if (HTo) {
            int d = tid >> 1, nh = (tid & 1) * 16;
            short tmp[16];
            #pragma unroll
            for (int i = 0; i < 16; ++i) tmp[i] = OUTb[(nh + i) * 136 + d];
            short* tdst = HTo + (size_t)(b * 128 + d) * 2048 + nt * 32 + nh;
            *(short8*)tdst = *(const short8*)tmp;
            *(short8*)(tdst + 8) = *(const short8*)(tmp + 8);
        }
        gbar(a.bar, 2 + l, bid);
    }

    // ================= mlp1: 32-row tile/block, 24 col-chunks of 64 =================
    {
        int m0 = bid * 32;
        short* A1 = smem;            // 32x128 = 4096
        short* B1 = smem + 4096;     // dbuf 2 x 8192 (64x128)
        int row16 = tid >> 4;
        // A stage (2 dma)
        #pragma unroll
        for (int q = 0; q < 2; ++q)
            dma16(a.HP3 + (size_t)(m0 + q * 16 + row16) * 128 + swz16,
                  A1 + q * 2048 + tid * 8);
        // B chunk 0 (4 dma)
        #pragma unroll
        for (int q = 0; q < 4; ++q)
            dma16(a.W1T + (size_t)(q * 16 + row16) * 128 + swz16,
                  B1 + q * 2048 + tid * 8);
        __syncthreads();

        for (int cc = 0; cc < 24; ++cc) {
            int cur = cc & 1, nxt = cur ^ 1;
            if (cc + 1 < 24) {
                #pragma unroll
                for (int q = 0; q < 4; ++q)
                    dma16(a.W1T + (size_t)((cc + 1) * 64 + q * 16 + row16) * 128 + swz16,
                          B1 + nxt * 8192 + q * 2048 + tid * 8);
            }
            const short* Bc = B1 + cur * 8192;
            floatx4 acc[2];
            #pragma unroll
            for (int j = 0; j < 2; ++j)
                #pragma unroll
                for (int r = 0; r < 4; ++r) acc[j][r] = 0.f;
            int Ra = wr * 16 + l15;
            #pragma unroll
            for (int ks = 0; ks < 4; ++ks) {
                int c16 = ks * 4 + quad;
                int sw = (((c16 & 8) | ((c16 ^ (l15 & 7)) & 7)) << 3);
                short8 af = *(const short8*)(A1 + Ra * 128 + sw);
                #pragma unroll
                for (int j = 0; j < 2; ++j) {
                    int Rb = wc * 32 + j * 16 + l15;
                    short8 bf = *(const short8*)(Bc + Rb * 128 + sw);
                    acc[j] = MFMA(af, bf, acc[j], 0, 0, 0);
                }
            }
            // store fp32 out
            #pragma unroll
            for (int j = 0; j < 2; ++j) {
                int col = cc * 64 + wc * 32 + j * 16 + l15;
                float bv = a.bm1[col];
                int r0 = wr * 16 + quad * 4;
                #pragma unroll
                for (int r = 0; r < 4; ++r) {
                    int m = m0 + r0 + r;  // n*4+b
                    int orow = (m & 3) * 2048 + (m >> 2);
                    a.out[(size_t)orow * 1536 + col] = acc[j][r] + bv;
                }
            }
            __syncthreads();
        }
    }
}

extern "C" void kernel_launch(void* const* d_in, const int* in_sizes, int n_in,
                              void* d_out, int out_size, void* d_ws, size_t ws_size,
                              hipStream_t stream) {
    char* ws = (char*)d_ws;
    size_t off = 0;
    auto alloc = [&](size_t bytes) -> char* {
        char* p = ws + off;
        off = (off + bytes + 255) & ~(size_t)255;
        return p;
    };
    Args a;
    a.bar  = (unsigned*)alloc(1024);
    a.adjS = (short*)alloc((size_t)2048 * 2048 * 2);
    a.W1T  = (short*)alloc((size_t)1536 * 128 * 2);
    a.BB0  = (short*)alloc(128 * 256 * 2);
    a.BB1  = (short*)alloc(128 * 256 * 2);
    a.BB2  = (short*)alloc(128 * 256 * 2);
    a.HP0  = (short*)alloc((size_t)8192 * 128 * 2);
    a.HP1  = (short*)alloc((size_t)8192 * 128 * 2);
    a.HP2  = (short*)alloc((size_t)8192 * 128 * 2);
    a.HP3  = (short*)alloc((size_t)8192 * 128 * 2);
    a.HT0  = (short*)alloc((size_t)512 * 2048 * 2);
    a.HT1  = (short*)alloc((size_t)512 * 2048 * 2);
    a.HT2  = (short*)alloc((size_t)512 * 2048 * 2);
    a.x   = (const float*)d_in[0];  a.adj = (const float*)d_in[1];
    a.W2  = (const float*)d_in[2];  a.b2v = (const float*)d_in[3];
    a.Wr0 = (const float*)d_in[4];  a.Wo0 = (const float*)d_in[5];
    a.lb1 = (const float*)d_in[6];  a.Wr1 = (const float*)d_in[7];
    a.Wo1 = (const float*)d_in[8];  a.lb2 = (const float*)d_in[9];
    a.Wr2 = (const float*)d_in[10]; a.Wo2 = (const float*)d_in[11];
    a.lb3 = (const float*)d_in[12]; a.W1  = (const float*)d_in[13];
    a.bm1 = (const float*)d_in[14];
    a.out = (float*)d_out;

    hipMemsetAsync(d_ws, 0, 1024, stream);
    mono2<<<256, 256, 0, stream>>>(a);
}